// Round 20
// baseline (637.787 us; speedup 1.0000x reference)
//
#include <hip/hip_runtime.h>
#include <cmath>

#define T_STEPS 8
#define NN 50000
#define EE 800000
#define NR 8          // node ranges (50000/8 = 6250 per range)
#define RSZ 6250
#define NSPLIT 4      // edge-list splits (800000/4 = 200000 per split)
#define QTR 200000
#define TXP 72        // padded Tx2 tile row stride (bank rotation; 144B = 16B-aligned)

typedef unsigned short ushort_t;
typedef unsigned int uint_t;
typedef __attribute__((ext_vector_type(8))) short s16x8;
typedef __attribute__((ext_vector_type(4))) float f32x4;

__device__ __forceinline__ float sigf(float x){ return 1.f/(1.f + __expf(-x)); }
__device__ __forceinline__ float tanhfast(float x){ return 1.f - 2.f/(1.f + __expf(2.f*x)); }

__device__ __forceinline__ ushort_t bf16_rne(float f){
    unsigned u = __float_as_uint(f);
    unsigned r = (u + 0x7fffu + ((u >> 16) & 1u)) >> 16;
    return (ushort_t)r;
}
__device__ __forceinline__ float bf16f(ushort_t h){ return __uint_as_float(((unsigned)h) << 16); }

__device__ __forceinline__ void gload_lds16(const void* g, void* l){
    __builtin_amdgcn_global_load_lds((const __attribute__((address_space(1))) void*)g,
                                     (__attribute__((address_space(3))) void*)l, 16, 0, 0);
}

// ---- Build weight fragments (bf16): Bh[ ((ks*16+nt)*64 + lane)*8 + e ] ----
__global__ void k_build_wfrag(const float* __restrict__ Wx, const float* __restrict__ Th,
                              const float* __restrict__ b, ushort_t* __restrict__ Bh,
                              float* __restrict__ bcat){
    int idx = blockIdx.x*blockDim.x + threadIdx.x;
    if (idx >= 256*256) return;
    int e    = idx & 7;
    int lane = (idx >> 3) & 63;
    int nt   = (idx >> 9) & 15;
    int ks   = idx >> 13;
    int k    = ks*32 + (lane >> 4)*8 + e;
    int col  = nt*16 + (lane & 15);
    int g = col >> 6, cc = col & 63, kb = k >> 6, kk = k & 63;
    float v = (kb == 0) ? Wx[(g*64 + kk)*64 + cc]
                        : Th[((g*3 + (kb-1))*64 + kk)*64 + cc];
    Bh[idx] = bf16_rne(v);
    if (idx < 256) bcat[idx] = b[idx];
}

// ---- LDS-binned degree (by src) + histogram (by dst); NO global atomics ----
__global__ __launch_bounds__(1024) void k_count(const int* __restrict__ ei,
        const float* __restrict__ wseq, float* __restrict__ degp, int* __restrict__ cntp){
    __shared__ float degb[RSZ];
    __shared__ int   cntb[RSZ];
    const int bid   = blockIdx.x;
    const int split = bid & 3;
    const int tt    = (bid >> 2) & 7;
    const int range = bid >> 5;
    const int nbase = range * RSZ;
    const int* src = ei + (size_t)tt*2*EE;
    const int* dst = src + EE;
    const float* w = wseq + (size_t)tt*EE;
    for (int i = threadIdx.x; i < RSZ; i += 1024){ degb[i] = 0.f; cntb[i] = 0; }
    __syncthreads();
    const int base = split*QTR;
    for (int e = base + threadIdx.x*16; e < base + QTR; e += 16384){
        int4   s4[4]; int4 d4[4]; float4 w4[4];
        #pragma unroll
        for (int u = 0; u < 4; ++u){
            s4[u] = *reinterpret_cast<const int4*>(src + e + u*4);
            d4[u] = *reinterpret_cast<const int4*>(dst + e + u*4);
            w4[u] = *reinterpret_cast<const float4*>(w + e + u*4);
        }
        #pragma unroll
        for (int u = 0; u < 4; ++u){
            const int ss[4] = {s4[u].x, s4[u].y, s4[u].z, s4[u].w};
            const int dd[4] = {d4[u].x, d4[u].y, d4[u].z, d4[u].w};
            const float ww[4] = {w4[u].x, w4[u].y, w4[u].z, w4[u].w};
            #pragma unroll
            for (int k = 0; k < 4; ++k){
                const unsigned su = (unsigned)(ss[k] - nbase), du = (unsigned)(dd[k] - nbase);
                if (su < (unsigned)RSZ) atomicAdd(&degb[su], ww[k]);
                if (du < (unsigned)RSZ) atomicAdd(&cntb[du], 1);
            }
        }
    }
    __syncthreads();
    float* dp = degp + ((size_t)tt*NSPLIT + split)*NN + nbase;
    int*   cp = cntp + ((size_t)tt*NSPLIT + split)*NN + nbase;
    for (int i = threadIdx.x; i < RSZ; i += 1024){ dp[i] = degb[i]; cp[i] = cntb[i]; }
}

// ---- scan stage 1: sum splits, dinv, block-local prefix; bsum = block totals ----
__global__ void k_scan1(const int* __restrict__ cntp, const float* __restrict__ degp,
                        float* __restrict__ dinv8, int* __restrict__ part8,
                        int* __restrict__ bsum8){
    __shared__ int s[256];
    int tt = blockIdx.y;
    int i = blockIdx.x*256 + threadIdx.x;
    int v = 0; float d = 0.f;
    if (i < NN){
        #pragma unroll
        for (int c = 0; c < NSPLIT; ++c){
            v += cntp[((size_t)tt*NSPLIT + c)*NN + i];
            d += degp[((size_t)tt*NSPLIT + c)*NN + i];
        }
    }
    s[threadIdx.x] = v; __syncthreads();
    #pragma unroll
    for (int off = 1; off < 256; off <<= 1){
        int t = (threadIdx.x >= off) ? s[threadIdx.x - off] : 0;
        __syncthreads();
        s[threadIdx.x] += t;
        __syncthreads();
    }
    if (i < NN){
        part8[(size_t)tt*NN + i] = s[threadIdx.x] - v;
        dinv8[(size_t)tt*NN + i] = d > 0.f ? rsqrtf(fmaxf(d, 1e-12f)) : 0.f;
    }
    if (threadIdx.x == 255) bsum8[tt*256 + blockIdx.x] = s[255];
}

// ---- scan stage 3 (scan2 folded in): each block reduces its own bsum prefix ----
__global__ void k_scan3(const int* __restrict__ part8, const int* __restrict__ bsum8,
                        const int* __restrict__ cntp, int* __restrict__ row_start8,
                        int* __restrict__ curp){
    __shared__ int sred[256];
    int tt = blockIdx.y;
    const int bid = blockIdx.x;
    int v0 = ((int)threadIdx.x < bid) ? bsum8[tt*256 + threadIdx.x] : 0;
    sred[threadIdx.x] = v0; __syncthreads();
    #pragma unroll
    for (int off = 128; off > 0; off >>= 1){
        if ((int)threadIdx.x < off) sred[threadIdx.x] += sred[threadIdx.x + off];
        __syncthreads();
    }
    const int base = sred[0];
    int i = bid*256 + threadIdx.x;
    if (i < NN){
        int v = part8[(size_t)tt*NN + i] + base;
        row_start8[(size_t)tt*(NN+1) + i] = v;
        #pragma unroll
        for (int c = 0; c < NSPLIT; ++c){
            const size_t k = ((size_t)tt*NSPLIT + c)*NN + i;
            curp[k] = v;
            v += cntp[k];
        }
    }
    if (i == 0) row_start8[(size_t)tt*(NN+1) + NN] = EE;
}

// ---- permute edges into node-major CSR; LDS cursors; 4B records ----
__global__ __launch_bounds__(1024) void k_perm(const int* __restrict__ ei,
        const float* __restrict__ wseq, const float* __restrict__ dinv8,
        const int* __restrict__ curp, uint_t* __restrict__ edat8){
    __shared__ int curb[RSZ];
    const int bid   = blockIdx.x;
    const int split = bid & 3;
    const int tt    = (bid >> 2) & 7;
    const int range = bid >> 5;
    const int nbase = range * RSZ;
    const int* src = ei + (size_t)tt*2*EE;
    const int* dst = src + EE;
    const float* w = wseq + (size_t)tt*EE;
    const float* dinv = dinv8 + (size_t)tt*NN;
    const int* cb = curp + ((size_t)tt*NSPLIT + split)*NN + nbase;
    for (int i = threadIdx.x; i < RSZ; i += 1024) curb[i] = cb[i];
    __syncthreads();
    uint_t* ed = edat8 + (size_t)tt*EE;
    const int base = split*QTR;
    for (int e = base + threadIdx.x*8; e < base + QTR; e += 8192){
        int4   s4[2]; int4 d4[2]; float4 w4[2];
        #pragma unroll
        for (int u = 0; u < 2; ++u){
            s4[u] = *reinterpret_cast<const int4*>(src + e + u*4);
            d4[u] = *reinterpret_cast<const int4*>(dst + e + u*4);
            w4[u] = *reinterpret_cast<const float4*>(w + e + u*4);
        }
        #pragma unroll
        for (int u = 0; u < 2; ++u){
            const int ss[4] = {s4[u].x, s4[u].y, s4[u].z, s4[u].w};
            const int dd[4] = {d4[u].x, d4[u].y, d4[u].z, d4[u].w};
            const float ww[4] = {w4[u].x, w4[u].y, w4[u].z, w4[u].w};
            #pragma unroll
            for (int k = 0; k < 4; ++k){
                const unsigned du = (unsigned)(dd[k] - nbase);
                if (du < (unsigned)RSZ){
                    const float nr = -dinv[ss[k]] * ww[k] * dinv[dd[k]];
                    const int p = atomicAdd(&curb[du], 1);
                    ed[p] = ((uint_t)bf16_rne(nr) << 16) | (uint_t)ss[k];
                }
            }
        }
    }
}

// ---- gather core: fp32 accumulate over one node's edge list (parity eo) ----
__device__ __forceinline__ float4 gather_q(const int* __restrict__ row_start,
        const uint_t* __restrict__ edat, const ushort_t* __restrict__ Xb,
        int n, int eo, int q){
    const int end = row_start[n+1];
    float4 acc = make_float4(0.f,0.f,0.f,0.f);
    for (int jj = row_start[n] + eo; jj < end; jj += 8){
        uint_t ra = edat[jj];
        uint_t rb = (jj+2 < end) ? edat[jj+2] : 0u;
        uint_t rc = (jj+4 < end) ? edat[jj+4] : 0u;
        uint_t rd = (jj+6 < end) ? edat[jj+6] : 0u;
        const ushort4 u0 = *reinterpret_cast<const ushort4*>(Xb + (size_t)(ra & 0xFFFFu)*64 + q);
        const ushort4 u1 = *reinterpret_cast<const ushort4*>(Xb + (size_t)(rb & 0xFFFFu)*64 + q);
        const ushort4 u2 = *reinterpret_cast<const ushort4*>(Xb + (size_t)(rc & 0xFFFFu)*64 + q);
        const ushort4 u3 = *reinterpret_cast<const ushort4*>(Xb + (size_t)(rd & 0xFFFFu)*64 + q);
        float sa = bf16f((ushort_t)(ra >> 16)), sb = bf16f((ushort_t)(rb >> 16));
        float sc = bf16f((ushort_t)(rc >> 16)), sd = bf16f((ushort_t)(rd >> 16));
        acc.x += sa*bf16f(u0.x) + sb*bf16f(u1.x) + sc*bf16f(u2.x) + sd*bf16f(u3.x);
        acc.y += sa*bf16f(u0.y) + sb*bf16f(u1.y) + sc*bf16f(u2.y) + sd*bf16f(u3.y);
        acc.z += sa*bf16f(u0.z) + sb*bf16f(u1.z) + sc*bf16f(u2.z) + sd*bf16f(u3.z);
        acc.w += sa*bf16f(u0.w) + sb*bf16f(u1.w) + sc*bf16f(u2.w) + sd*bf16f(u3.w);
    }
    return acc;
}

// ---- standalone SpMV (used for Tx1 = A*H): 32 thr/node ----
__global__ __launch_bounds__(256) void k_spmv_g(
        const int* __restrict__ row_start, const uint_t* __restrict__ edat,
        const ushort_t* __restrict__ Xb, ushort_t* __restrict__ outb, int N){
    int gid = blockIdx.x*blockDim.x + threadIdx.x;
    int n = gid >> 5;
    if (n >= N) return;
    const int ln = gid & 31;
    const int eo = ln >> 4;
    const int q  = (ln & 15) << 2;
    float4 acc = gather_q(row_start, edat, Xb, n, eo, q);
    acc.x += __shfl_xor(acc.x, 16);
    acc.y += __shfl_xor(acc.y, 16);
    acc.z += __shfl_xor(acc.z, 16);
    acc.w += __shfl_xor(acc.w, 16);
    if (eo == 0){
        ushort4 rb4;
        rb4.x = bf16_rne(acc.x); rb4.y = bf16_rne(acc.y);
        rb4.z = bf16_rne(acc.z); rb4.w = bf16_rne(acc.w);
        *reinterpret_cast<ushort4*>(outb + (size_t)n*64 + q) = rb4;
    }
}

// ---- fused: Tx2 tile gather (spmv2) + MFMA GEMM + LSTM epilogue ----
// Phase 0 (t>0): compute Tx2[bm..bm+127] = 2*A*Tx1 - H into LDS (padded tile).
// Then GEMM over [x | H | Tx1 | Tx2_lds] with bf16 B; LSTM epilogue.
__global__ __launch_bounds__(512) void k_gemm_mfma(
        const float* __restrict__ x, ushort_t* __restrict__ Hb,
        const ushort_t* __restrict__ Tx1b, const ushort_t* __restrict__ Bh,
        const float* __restrict__ bcat, const float* __restrict__ wc,
        ushort_t* __restrict__ Cb, float* __restrict__ out,
        const int* __restrict__ row_start, const uint_t* __restrict__ edat,
        int N, int first, int last){
    __shared__ ushort_t Bs[2][8192];       // 32KB B double-buffer
    __shared__ ushort_t txs[128*TXP];      // 18KB padded Tx2 tile
    const int t  = threadIdx.x;
    const int w  = t >> 6;        // wave 0..7
    const int l  = t & 63;
    const int lr = l & 15;
    const int lg = l >> 4;
    const int bm = blockIdx.x * 128;
    const int arow = bm + w*16 + lr;
    const bool valid = arow < N;

    // ---- phase 0: Tx2 tile (skip at t==0: state is zero) ----
    if (!first){
        for (int s = t; s < 128*32; s += 512){
            const int rl = s >> 5;
            const int n  = bm + rl;
            const int ln = s & 31;
            const int eo = ln >> 4;
            const int q  = (ln & 15) << 2;
            float4 acc = make_float4(0.f,0.f,0.f,0.f);
            if (n < N) acc = gather_q(row_start, edat, Tx1b, n, eo, q);
            acc.x += __shfl_xor(acc.x, 16);
            acc.y += __shfl_xor(acc.y, 16);
            acc.z += __shfl_xor(acc.z, 16);
            acc.w += __shfl_xor(acc.w, 16);
            if (eo == 0 && n < N){
                const ushort4 h = *reinterpret_cast<const ushort4*>(Hb + (size_t)n*64 + q);
                ushort4 r;
                r.x = bf16_rne(2.f*acc.x - bf16f(h.x));
                r.y = bf16_rne(2.f*acc.y - bf16f(h.y));
                r.z = bf16_rne(2.f*acc.z - bf16f(h.z));
                r.w = bf16_rne(2.f*acc.w - bf16f(h.w));
                *reinterpret_cast<ushort4*>(&txs[rl*TXP + q]) = r;
            }
        }
    }

    f32x4 acc[16];
    #pragma unroll
    for (int i = 0; i < 16; ++i) acc[i] = (f32x4){0.f,0.f,0.f,0.f};

    #define STAGE(ks_, buf_) {                                                   \
        const size_t sl = (size_t)(ks_)*8192;                                    \
        _Pragma("unroll")                                                        \
        for (int c = 0; c < 2; ++c){                                             \
            const int ch = (w*2 + c)*512;                                        \
            gload_lds16(Bh + sl + ch + l*8, &Bs[buf_][ch]);                      \
        }                                                                        \
    }

    const s16x8 zero8 = (s16x8){0,0,0,0,0,0,0,0};
    float4 vx0, vx1, nx0, nx1;
    s16x8  vb = zero8, nb = zero8;

    STAGE(0, 0);
    {
        const int kk = lg*8;
        if (valid){
            vx0 = *reinterpret_cast<const float4*>(x + (size_t)arow*64 + kk);
            vx1 = *reinterpret_cast<const float4*>(x + (size_t)arow*64 + kk + 4);
        } else { vx0 = vx1 = make_float4(0.f,0.f,0.f,0.f); }
    }

    const int ksmax = first ? 2 : 8;
    const int trow = w*16 + lr;
    for (int ks = 0; ks < 8; ++ks){
        const int buf = ks & 1;
        __syncthreads();   // drains phase-0 LDS writes (ks==0) + B stage + prior reads
        if (ks < 7){
            STAGE(ks+1, buf^1);
            const int nkt = (ks+1) >> 1;
            const int nkk = ((ks+1) & 1)*32 + lg*8;
            if (nkt == 0){
                if (valid){
                    nx0 = *reinterpret_cast<const float4*>(x + (size_t)arow*64 + nkk);
                    nx1 = *reinterpret_cast<const float4*>(x + (size_t)arow*64 + nkk + 4);
                } else { nx0 = nx1 = make_float4(0.f,0.f,0.f,0.f); }
            } else if (!first){
                if (nkt == 3){   // Tx2 from LDS tile
                    nb = valid ? *reinterpret_cast<const s16x8*>(&txs[trow*TXP + nkk])
                               : zero8;
                } else {
                    const ushort_t* sp = (nkt==1) ? Hb : Tx1b;
                    nb = valid ? *reinterpret_cast<const s16x8*>(sp + (size_t)arow*64 + nkk)
                               : zero8;
                }
            }
        }
        if (ks < ksmax){
            s16x8 ah;
            if (ks < 2){
                float va[8] = {vx0.x, vx0.y, vx0.z, vx0.w, vx1.x, vx1.y, vx1.z, vx1.w};
                #pragma unroll
                for (int e = 0; e < 8; ++e) ah[e] = (short)bf16_rne(va[e]);
            } else {
                ah = vb;
            }
            #pragma unroll
            for (int nt = 0; nt < 16; ++nt){
                const s16x8 bh = *reinterpret_cast<const s16x8*>(&Bs[buf][(nt*64 + l)*8]);
                acc[nt] = __builtin_amdgcn_mfma_f32_16x16x32_bf16(ah, bh, acc[nt], 0, 0, 0);
            }
        }
        vx0 = nx0; vx1 = nx1; vb = nb;
    }
    #undef STAGE

    const int rbase = bm + w*16 + lg*4;
    #pragma unroll
    for (int cq = 0; cq < 4; ++cq){
        const int c = lr + 16*cq;
        const float b0 = bcat[c], b1 = bcat[64+c], b2 = bcat[128+c], b3 = bcat[192+c];
        const float w0 = wc[c], w1 = wc[64+c], w2v = wc[128+c];
        #pragma unroll
        for (int r = 0; r < 4; ++r){
            const int rowi = rbase + r;
            if (rowi >= N) continue;
            const size_t idx = (size_t)rowi*64 + c;
            const float cold = first ? 0.f : bf16f(Cb[idx]);
            const float z0 = acc[cq][r]     + b0;
            const float z1 = acc[4+cq][r]   + b1;
            const float z2 = acc[8+cq][r]   + b2;
            const float z3 = acc[12+cq][r]  + b3;
            const float i_ = sigf(z0 + w0*cold);
            const float f_ = sigf(z1 + w1*cold);
            const float g_ = tanhfast(z2);
            const float cn = f_*cold + i_*g_;
            const float o_ = sigf(z3 + w2v*cn);
            const float hn = o_*tanhfast(cn);
            Cb[idx] = bf16_rne(cn);
            Hb[idx] = bf16_rne(hn);
            if (last) out[idx] = fmaxf(hn, 0.f);
        }
    }
}

extern "C" void kernel_launch(void* const* d_in, const int* in_sizes, int n_in,
                              void* d_out, int out_size, void* d_ws, size_t ws_size,
                              hipStream_t stream){
    const float* x_seq = (const float*)d_in[0];
    const float* w_seq = (const float*)d_in[1];
    const float* Wx    = (const float*)d_in[2];
    const float* Th    = (const float*)d_in[3];
    const float* b     = (const float*)d_in[4];
    const float* wc    = (const float*)d_in[5];
    const int*   ei    = (const int*)d_in[6];
    float* out = (float*)d_out;

    float* ws = (float*)d_ws;
    size_t off = 0;   // in floats
    ushort_t* Cb    = (ushort_t*)(ws + off); off += (size_t)NN*32;   // bf16, 6.4MB
    ushort_t* Hb    = (ushort_t*)(ws + off); off += (size_t)NN*32;
    ushort_t* Tx1b  = (ushort_t*)(ws + off); off += (size_t)NN*32;
    ushort_t* pad0  = (ushort_t*)(ws + off); off += (size_t)NN*32;   // alias space only
    (void)pad0;
    ushort_t* Bh    = (ushort_t*)(ws + off); off += 256*256/2;
    float* bcat     = ws + off; off += 256;
    uint_t* edat8     = (uint_t*)(ws + off); off += (size_t)T_STEPS*EE;  // 4B records
    int*   row_start8 = (int*)(ws + off);  off += (size_t)T_STEPS*(NN+1);
    // prep-only scratch aliases [Cb|Hb|Tx1b|pad0] (dead until after prep; 25.6MB >= 22.4MB)
    float* pr = (float*)Cb;
    size_t po = 0;
    float* degp  = pr + po; po += (size_t)T_STEPS*NSPLIT*NN;
    int*   cntp  = (int*)(pr + po); po += (size_t)T_STEPS*NSPLIT*NN;
    int*   curp  = (int*)(pr + po); po += (size_t)T_STEPS*NSPLIT*NN;
    float* dinv8 = pr + po; po += (size_t)T_STEPS*NN;
    int*   part8 = (int*)(pr + po); po += (size_t)T_STEPS*NN;
    int*   bsum8 = (int*)(pr + po); po += (size_t)T_STEPS*256;

    const int NB = (NN + 255)/256;

    k_build_wfrag<<<256, 256, 0, stream>>>(Wx, Th, b, Bh, bcat);

    // batched graph prep, no global atomics; slice-grouped XCD decode
    k_count<<<NR*NSPLIT*T_STEPS, 1024, 0, stream>>>(ei, w_seq, degp, cntp);
    k_scan1<<<dim3(NB, T_STEPS), 256, 0, stream>>>(cntp, degp, dinv8, part8, bsum8);
    k_scan3<<<dim3(NB, T_STEPS), 256, 0, stream>>>(part8, bsum8, cntp, row_start8, curp);
    k_perm <<<NR*NSPLIT*T_STEPS, 1024, 0, stream>>>(ei, w_seq, dinv8, curp, edat8);

    // No state memsets: t==0 gemm runs in `first` mode (writes Cb/Hb fully);
    // Tx1b written by t==1's spmv before first read; Tx2 lives in LDS only.

    for (int t = 0; t < T_STEPS; ++t){
        const int* rs = row_start8 + (size_t)t*(NN+1);
        const uint_t* ed = edat8 + (size_t)t*EE;
        const float* x = x_seq + (size_t)t*NN*64;

        if (t > 0)
            k_spmv_g<<<(NN*32+255)/256, 256, 0, stream>>>(rs, ed, Hb, Tx1b, NN);
        k_gemm_mfma<<<(NN+127)/128, 512, 0, stream>>>(x, Hb, Tx1b, Bh, bcat, wc,
                                                      Cb, out, rs, ed, NN,
                                                      t==0, t==T_STEPS-1);
    }
}

// Round 21
// 587.072 us; speedup vs baseline: 1.0864x; 1.0864x over previous
//
#include <hip/hip_runtime.h>
#include <cmath>

#define T_STEPS 8
#define NN 50000
#define EE 800000
#define NR 8          // node ranges (50000/8 = 6250 per range)
#define RSZ 6250
#define NSPLIT 4      // edge-list splits (800000/4 = 200000 per split)
#define QTR 200000

typedef unsigned short ushort_t;
typedef unsigned int uint_t;
typedef __attribute__((ext_vector_type(8))) short s16x8;
typedef __attribute__((ext_vector_type(4))) float f32x4;

__device__ __forceinline__ float sigf(float x){ return 1.f/(1.f + __expf(-x)); }
__device__ __forceinline__ float tanhfast(float x){ return 1.f - 2.f/(1.f + __expf(2.f*x)); }

__device__ __forceinline__ ushort_t bf16_rne(float f){
    unsigned u = __float_as_uint(f);
    unsigned r = (u + 0x7fffu + ((u >> 16) & 1u)) >> 16;
    return (ushort_t)r;
}
__device__ __forceinline__ float bf16f(ushort_t h){ return __uint_as_float(((unsigned)h) << 16); }

__device__ __forceinline__ void gload_lds16(const void* g, void* l){
    __builtin_amdgcn_global_load_lds((const __attribute__((address_space(1))) void*)g,
                                     (__attribute__((address_space(3))) void*)l, 16, 0, 0);
}

// ---- Build weight fragments (bf16): Bh[ ((ks*16+nt)*64 + lane)*8 + e ] ----
__global__ void k_build_wfrag(const float* __restrict__ Wx, const float* __restrict__ Th,
                              const float* __restrict__ b, ushort_t* __restrict__ Bh,
                              float* __restrict__ bcat){
    int idx = blockIdx.x*blockDim.x + threadIdx.x;
    if (idx >= 256*256) return;
    int e    = idx & 7;
    int lane = (idx >> 3) & 63;
    int nt   = (idx >> 9) & 15;
    int ks   = idx >> 13;
    int k    = ks*32 + (lane >> 4)*8 + e;
    int col  = nt*16 + (lane & 15);
    int g = col >> 6, cc = col & 63, kb = k >> 6, kk = k & 63;
    float v = (kb == 0) ? Wx[(g*64 + kk)*64 + cc]
                        : Th[((g*3 + (kb-1))*64 + kk)*64 + cc];
    Bh[idx] = bf16_rne(v);
    if (idx < 256) bcat[idx] = b[idx];
}

// ---- LDS-binned degree (by src) + histogram (by dst); NO global atomics ----
__global__ __launch_bounds__(1024) void k_count(const int* __restrict__ ei,
        const float* __restrict__ wseq, float* __restrict__ degp, int* __restrict__ cntp){
    __shared__ float degb[RSZ];
    __shared__ int   cntb[RSZ];
    const int bid   = blockIdx.x;
    const int split = bid & 3;
    const int tt    = (bid >> 2) & 7;
    const int range = bid >> 5;
    const int nbase = range * RSZ;
    const int* src = ei + (size_t)tt*2*EE;
    const int* dst = src + EE;
    const float* w = wseq + (size_t)tt*EE;
    for (int i = threadIdx.x; i < RSZ; i += 1024){ degb[i] = 0.f; cntb[i] = 0; }
    __syncthreads();
    const int base = split*QTR;
    for (int e = base + threadIdx.x*16; e < base + QTR; e += 16384){
        int4   s4[4]; int4 d4[4]; float4 w4[4];
        #pragma unroll
        for (int u = 0; u < 4; ++u){
            s4[u] = *reinterpret_cast<const int4*>(src + e + u*4);
            d4[u] = *reinterpret_cast<const int4*>(dst + e + u*4);
            w4[u] = *reinterpret_cast<const float4*>(w + e + u*4);
        }
        #pragma unroll
        for (int u = 0; u < 4; ++u){
            const int ss[4] = {s4[u].x, s4[u].y, s4[u].z, s4[u].w};
            const int dd[4] = {d4[u].x, d4[u].y, d4[u].z, d4[u].w};
            const float ww[4] = {w4[u].x, w4[u].y, w4[u].z, w4[u].w};
            #pragma unroll
            for (int k = 0; k < 4; ++k){
                const unsigned su = (unsigned)(ss[k] - nbase), du = (unsigned)(dd[k] - nbase);
                if (su < (unsigned)RSZ) atomicAdd(&degb[su], ww[k]);
                if (du < (unsigned)RSZ) atomicAdd(&cntb[du], 1);
            }
        }
    }
    __syncthreads();
    float* dp = degp + ((size_t)tt*NSPLIT + split)*NN + nbase;
    int*   cp = cntp + ((size_t)tt*NSPLIT + split)*NN + nbase;
    for (int i = threadIdx.x; i < RSZ; i += 1024){ dp[i] = degb[i]; cp[i] = cntb[i]; }
}

// ---- scan stage 1: sum splits, dinv, block-local prefix; bsum = block totals ----
__global__ void k_scan1(const int* __restrict__ cntp, const float* __restrict__ degp,
                        float* __restrict__ dinv8, int* __restrict__ part8,
                        int* __restrict__ bsum8){
    __shared__ int s[256];
    int tt = blockIdx.y;
    int i = blockIdx.x*256 + threadIdx.x;
    int v = 0; float d = 0.f;
    if (i < NN){
        #pragma unroll
        for (int c = 0; c < NSPLIT; ++c){
            v += cntp[((size_t)tt*NSPLIT + c)*NN + i];
            d += degp[((size_t)tt*NSPLIT + c)*NN + i];
        }
    }
    s[threadIdx.x] = v; __syncthreads();
    #pragma unroll
    for (int off = 1; off < 256; off <<= 1){
        int t = (threadIdx.x >= off) ? s[threadIdx.x - off] : 0;
        __syncthreads();
        s[threadIdx.x] += t;
        __syncthreads();
    }
    if (i < NN){
        part8[(size_t)tt*NN + i] = s[threadIdx.x] - v;
        dinv8[(size_t)tt*NN + i] = d > 0.f ? rsqrtf(fmaxf(d, 1e-12f)) : 0.f;
    }
    if (threadIdx.x == 255) bsum8[tt*256 + blockIdx.x] = s[255];
}

// ---- scan stage 3 (scan2 folded in): each block reduces its own bsum prefix ----
__global__ void k_scan3(const int* __restrict__ part8, const int* __restrict__ bsum8,
                        const int* __restrict__ cntp, int* __restrict__ row_start8,
                        int* __restrict__ curp){
    __shared__ int sred[256];
    int tt = blockIdx.y;
    const int bid = blockIdx.x;
    int v0 = ((int)threadIdx.x < bid) ? bsum8[tt*256 + threadIdx.x] : 0;
    sred[threadIdx.x] = v0; __syncthreads();
    #pragma unroll
    for (int off = 128; off > 0; off >>= 1){
        if ((int)threadIdx.x < off) sred[threadIdx.x] += sred[threadIdx.x + off];
        __syncthreads();
    }
    const int base = sred[0];
    int i = bid*256 + threadIdx.x;
    if (i < NN){
        int v = part8[(size_t)tt*NN + i] + base;
        row_start8[(size_t)tt*(NN+1) + i] = v;
        #pragma unroll
        for (int c = 0; c < NSPLIT; ++c){
            const size_t k = ((size_t)tt*NSPLIT + c)*NN + i;
            curp[k] = v;
            v += cntp[k];
        }
    }
    if (i == 0) row_start8[(size_t)tt*(NN+1) + NN] = EE;
}

// ---- permute edges into node-major CSR; LDS cursors; 4B records ----
__global__ __launch_bounds__(1024) void k_perm(const int* __restrict__ ei,
        const float* __restrict__ wseq, const float* __restrict__ dinv8,
        const int* __restrict__ curp, uint_t* __restrict__ edat8){
    __shared__ int curb[RSZ];
    const int bid   = blockIdx.x;
    const int split = bid & 3;
    const int tt    = (bid >> 2) & 7;
    const int range = bid >> 5;
    const int nbase = range * RSZ;
    const int* src = ei + (size_t)tt*2*EE;
    const int* dst = src + EE;
    const float* w = wseq + (size_t)tt*EE;
    const float* dinv = dinv8 + (size_t)tt*NN;
    const int* cb = curp + ((size_t)tt*NSPLIT + split)*NN + nbase;
    for (int i = threadIdx.x; i < RSZ; i += 1024) curb[i] = cb[i];
    __syncthreads();
    uint_t* ed = edat8 + (size_t)tt*EE;
    const int base = split*QTR;
    for (int e = base + threadIdx.x*8; e < base + QTR; e += 8192){
        int4   s4[2]; int4 d4[2]; float4 w4[2];
        #pragma unroll
        for (int u = 0; u < 2; ++u){
            s4[u] = *reinterpret_cast<const int4*>(src + e + u*4);
            d4[u] = *reinterpret_cast<const int4*>(dst + e + u*4);
            w4[u] = *reinterpret_cast<const float4*>(w + e + u*4);
        }
        #pragma unroll
        for (int u = 0; u < 2; ++u){
            const int ss[4] = {s4[u].x, s4[u].y, s4[u].z, s4[u].w};
            const int dd[4] = {d4[u].x, d4[u].y, d4[u].z, d4[u].w};
            const float ww[4] = {w4[u].x, w4[u].y, w4[u].z, w4[u].w};
            #pragma unroll
            for (int k = 0; k < 4; ++k){
                const unsigned du = (unsigned)(dd[k] - nbase);
                if (du < (unsigned)RSZ){
                    const float nr = -dinv[ss[k]] * ww[k] * dinv[dd[k]];
                    const int p = atomicAdd(&curb[du], 1);
                    ed[p] = ((uint_t)bf16_rne(nr) << 16) | (uint_t)ss[k];
                }
            }
        }
    }
}

// ---- gather SpMV (bf16): 32 thr/node = 2 edge-parity x 16 feature lanes;
// masked unroll-4 (no scalar tail: zero-record gathers are free/cached). ----
__global__ __launch_bounds__(256) void k_spmv_g(
        const int* __restrict__ row_start, const uint_t* __restrict__ edat,
        const ushort_t* __restrict__ Xb, const ushort_t* __restrict__ Hsb,
        ushort_t* __restrict__ outb, int N, float scale, int sub){
    int gid = blockIdx.x*blockDim.x + threadIdx.x;
    int n = gid >> 5;
    if (n >= N) return;
    const int ln = gid & 31;
    const int eo = ln >> 4;          // edge parity 0/1
    const int q  = (ln & 15) << 2;   // feature quarter (4 bf16)
    const int end = row_start[n+1];
    float4 acc = make_float4(0.f,0.f,0.f,0.f);
    for (int jj = row_start[n] + eo; jj < end; jj += 8){
        uint_t ra = edat[jj];
        uint_t rb = (jj+2 < end) ? edat[jj+2] : 0u;
        uint_t rc = (jj+4 < end) ? edat[jj+4] : 0u;
        uint_t rd = (jj+6 < end) ? edat[jj+6] : 0u;
        const ushort4 u0 = *reinterpret_cast<const ushort4*>(Xb + (size_t)(ra & 0xFFFFu)*64 + q);
        const ushort4 u1 = *reinterpret_cast<const ushort4*>(Xb + (size_t)(rb & 0xFFFFu)*64 + q);
        const ushort4 u2 = *reinterpret_cast<const ushort4*>(Xb + (size_t)(rc & 0xFFFFu)*64 + q);
        const ushort4 u3 = *reinterpret_cast<const ushort4*>(Xb + (size_t)(rd & 0xFFFFu)*64 + q);
        float sa = bf16f((ushort_t)(ra >> 16)), sb = bf16f((ushort_t)(rb >> 16));
        float sc = bf16f((ushort_t)(rc >> 16)), sd = bf16f((ushort_t)(rd >> 16));
        acc.x += sa*bf16f(u0.x) + sb*bf16f(u1.x) + sc*bf16f(u2.x) + sd*bf16f(u3.x);
        acc.y += sa*bf16f(u0.y) + sb*bf16f(u1.y) + sc*bf16f(u2.y) + sd*bf16f(u3.y);
        acc.z += sa*bf16f(u0.z) + sb*bf16f(u1.z) + sc*bf16f(u2.z) + sd*bf16f(u3.z);
        acc.w += sa*bf16f(u0.w) + sb*bf16f(u1.w) + sc*bf16f(u2.w) + sd*bf16f(u3.w);
    }
    acc.x += __shfl_xor(acc.x, 16);
    acc.y += __shfl_xor(acc.y, 16);
    acc.z += __shfl_xor(acc.z, 16);
    acc.w += __shfl_xor(acc.w, 16);
    if (eo == 0){
        float4 r;
        if (sub){
            const ushort4 h = *reinterpret_cast<const ushort4*>(Hsb + (size_t)n*64 + q);
            r.x = scale*acc.x - bf16f(h.x); r.y = scale*acc.y - bf16f(h.y);
            r.z = scale*acc.z - bf16f(h.z); r.w = scale*acc.w - bf16f(h.w);
        } else {
            r.x = scale*acc.x; r.y = scale*acc.y; r.z = scale*acc.z; r.w = scale*acc.w;
        }
        ushort4 rb;
        rb.x = bf16_rne(r.x); rb.y = bf16_rne(r.y);
        rb.z = bf16_rne(r.z); rb.w = bf16_rne(r.w);
        *reinterpret_cast<ushort4*>(outb + (size_t)n*64 + q) = rb;
    }
}

// ---- fused MFMA GEMM + LSTM epilogue; bf16 B single-plane; bf16 A; bf16 C;
// first-step fast path (state==0: skip state loads + C read). ----
__global__ __launch_bounds__(512) void k_gemm_mfma(
        const float* __restrict__ x, ushort_t* __restrict__ Hb,
        const ushort_t* __restrict__ Tx1b, const ushort_t* __restrict__ Tx2b,
        const ushort_t* __restrict__ Bh,
        const float* __restrict__ bcat, const float* __restrict__ wc,
        ushort_t* __restrict__ Cb, float* __restrict__ out, int N,
        int first, int last){
    __shared__ ushort_t Bs[2][8192];   // [buf][16KB]
    const int t  = threadIdx.x;
    const int w  = t >> 6;        // wave 0..7
    const int l  = t & 63;
    const int lr = l & 15;
    const int lg = l >> 4;
    const int bm = blockIdx.x * 128;
    const int arow = bm + w*16 + lr;
    const bool valid = arow < N;

    f32x4 acc[16];
    #pragma unroll
    for (int i = 0; i < 16; ++i) acc[i] = (f32x4){0.f,0.f,0.f,0.f};

    #define STAGE(ks_, buf_) {                                                   \
        const size_t sl = (size_t)(ks_)*8192;                                    \
        _Pragma("unroll")                                                        \
        for (int c = 0; c < 2; ++c){                                             \
            const int ch = (w*2 + c)*512;                                        \
            gload_lds16(Bh + sl + ch + l*8, &Bs[buf_][ch]);                      \
        }                                                                        \
    }

    const s16x8 zero8 = (s16x8){0,0,0,0,0,0,0,0};
    float4 vx0, vx1, nx0, nx1;
    s16x8  vb = zero8, nb = zero8;

    STAGE(0, 0);
    {
        const int kk = lg*8;
        if (valid){
            vx0 = *reinterpret_cast<const float4*>(x + (size_t)arow*64 + kk);
            vx1 = *reinterpret_cast<const float4*>(x + (size_t)arow*64 + kk + 4);
        } else { vx0 = vx1 = make_float4(0.f,0.f,0.f,0.f); }
    }

    const int ksmax = first ? 2 : 8;   // first step: state==0, only x contributes
    for (int ks = 0; ks < 8; ++ks){
        const int buf = ks & 1;
        __syncthreads();
        if (ks < 7){
            STAGE(ks+1, buf^1);
            const int nkt = (ks+1) >> 1;
            const int nkk = ((ks+1) & 1)*32 + lg*8;
            if (nkt == 0){
                if (valid){
                    nx0 = *reinterpret_cast<const float4*>(x + (size_t)arow*64 + nkk);
                    nx1 = *reinterpret_cast<const float4*>(x + (size_t)arow*64 + nkk + 4);
                } else { nx0 = nx1 = make_float4(0.f,0.f,0.f,0.f); }
            } else if (!first){
                const ushort_t* sp = (nkt==1) ? Hb : (nkt==2) ? Tx1b : Tx2b;
                nb = valid ? *reinterpret_cast<const s16x8*>(sp + (size_t)arow*64 + nkk)
                           : zero8;
            }
        }
        if (ks < ksmax){
            s16x8 ah;
            if (ks < 2){
                float va[8] = {vx0.x, vx0.y, vx0.z, vx0.w, vx1.x, vx1.y, vx1.z, vx1.w};
                #pragma unroll
                for (int e = 0; e < 8; ++e) ah[e] = (short)bf16_rne(va[e]);
            } else {
                ah = vb;
            }
            #pragma unroll
            for (int nt = 0; nt < 16; ++nt){
                const s16x8 bh = *reinterpret_cast<const s16x8*>(&Bs[buf][(nt*64 + l)*8]);
                acc[nt] = __builtin_amdgcn_mfma_f32_16x16x32_bf16(ah, bh, acc[nt], 0, 0, 0);
            }
        }
        vx0 = nx0; vx1 = nx1; vb = nb;
    }
    #undef STAGE

    const int rbase = bm + w*16 + lg*4;
    #pragma unroll
    for (int cq = 0; cq < 4; ++cq){
        const int c = lr + 16*cq;
        const float b0 = bcat[c], b1 = bcat[64+c], b2 = bcat[128+c], b3 = bcat[192+c];
        const float w0 = wc[c], w1 = wc[64+c], w2v = wc[128+c];
        #pragma unroll
        for (int r = 0; r < 4; ++r){
            const int rowi = rbase + r;
            if (rowi >= N) continue;
            const size_t idx = (size_t)rowi*64 + c;
            const float cold = first ? 0.f : bf16f(Cb[idx]);
            const float z0 = acc[cq][r]     + b0;
            const float z1 = acc[4+cq][r]   + b1;
            const float z2 = acc[8+cq][r]   + b2;
            const float z3 = acc[12+cq][r]  + b3;
            const float i_ = sigf(z0 + w0*cold);
            const float f_ = sigf(z1 + w1*cold);
            const float g_ = tanhfast(z2);
            const float cn = f_*cold + i_*g_;
            const float o_ = sigf(z3 + w2v*cn);
            const float hn = o_*tanhfast(cn);
            Cb[idx] = bf16_rne(cn);
            Hb[idx] = bf16_rne(hn);
            if (last) out[idx] = fmaxf(hn, 0.f);
        }
    }
}

extern "C" void kernel_launch(void* const* d_in, const int* in_sizes, int n_in,
                              void* d_out, int out_size, void* d_ws, size_t ws_size,
                              hipStream_t stream){
    const float* x_seq = (const float*)d_in[0];
    const float* w_seq = (const float*)d_in[1];
    const float* Wx    = (const float*)d_in[2];
    const float* Th    = (const float*)d_in[3];
    const float* b     = (const float*)d_in[4];
    const float* wc    = (const float*)d_in[5];
    const int*   ei    = (const int*)d_in[6];
    float* out = (float*)d_out;

    float* ws = (float*)d_ws;
    size_t off = 0;   // in floats
    ushort_t* Cb    = (ushort_t*)(ws + off); off += (size_t)NN*32;   // bf16, 6.4MB
    ushort_t* Hb    = (ushort_t*)(ws + off); off += (size_t)NN*32;
    ushort_t* Tx1b  = (ushort_t*)(ws + off); off += (size_t)NN*32;
    ushort_t* Tx2b  = (ushort_t*)(ws + off); off += (size_t)NN*32;
    ushort_t* Bh    = (ushort_t*)(ws + off); off += 256*256/2;
    float* bcat     = ws + off; off += 256;
    uint_t* edat8     = (uint_t*)(ws + off); off += (size_t)T_STEPS*EE;  // 4B records
    int*   row_start8 = (int*)(ws + off);  off += (size_t)T_STEPS*(NN+1);
    // prep-only scratch aliases [Cb|Hb|Tx1b|Tx2b] (dead until after prep; 25.6MB >= 22.4MB)
    float* pr = (float*)Cb;
    size_t po = 0;
    float* degp  = pr + po; po += (size_t)T_STEPS*NSPLIT*NN;
    int*   cntp  = (int*)(pr + po); po += (size_t)T_STEPS*NSPLIT*NN;
    int*   curp  = (int*)(pr + po); po += (size_t)T_STEPS*NSPLIT*NN;
    float* dinv8 = pr + po; po += (size_t)T_STEPS*NN;
    int*   part8 = (int*)(pr + po); po += (size_t)T_STEPS*NN;
    int*   bsum8 = (int*)(pr + po); po += (size_t)T_STEPS*256;

    const int NB = (NN + 255)/256;

    k_build_wfrag<<<256, 256, 0, stream>>>(Wx, Th, b, Bh, bcat);

    // batched graph prep, no global atomics; slice-grouped XCD decode
    k_count<<<NR*NSPLIT*T_STEPS, 1024, 0, stream>>>(ei, w_seq, degp, cntp);
    k_scan1<<<dim3(NB, T_STEPS), 256, 0, stream>>>(cntp, degp, dinv8, part8, bsum8);
    k_scan3<<<dim3(NB, T_STEPS), 256, 0, stream>>>(part8, bsum8, cntp, row_start8, curp);
    k_perm <<<NR*NSPLIT*T_STEPS, 1024, 0, stream>>>(ei, w_seq, dinv8, curp, edat8);

    // No state memsets: t==0 gemm runs in `first` mode (reads only x, writes
    // Cb/Hb fully); Tx1b/Tx2b are written by t==1's spmvs before first read.

    for (int t = 0; t < T_STEPS; ++t){
        const int* rs = row_start8 + (size_t)t*(NN+1);
        const uint_t* ed = edat8 + (size_t)t*EE;
        const float* x = x_seq + (size_t)t*NN*64;

        if (t > 0){
            k_spmv_g<<<(NN*32+255)/256, 256, 0, stream>>>(rs, ed, Hb,   Hb, Tx1b, NN, 1.0f, 0);
            k_spmv_g<<<(NN*32+255)/256, 256, 0, stream>>>(rs, ed, Tx1b, Hb, Tx2b, NN, 2.0f, 1);
        }
        k_gemm_mfma<<<(NN+127)/128, 512, 0, stream>>>(x, Hb, Tx1b, Tx2b, Bh, bcat, wc,
                                                      Cb, out, NN, t==0, t==T_STEPS-1);
    }
}